// Round 14
// baseline (50.979 us; speedup 1.0000x reference)
//
#include <hip/hip_runtime.h>
#include <hip/hip_bf16.h>

// N=8192 points, k=8 exact kNN -> mean |plane distance|.
// R14: SINGLE-KERNEL MFMA-filtered exact kNN. 512 blocks x 512 threads; each
// block owns 16 rows end-to-end: in-block threshold (512 samples/row), 16
// stages of 512 cols (pack B-frags from means on the fly into LDS), 16x16x32
// bf16 MFMA filter -> register bitmask -> intra-wave decode + exact f32
// rescore -> xor/LDS merges -> plane distance -> one atomicAdd per block.
// No intermediate global arrays, no multi-kernel pipeline.
//   d2(r,c) = sq_r + sq_c - 2 p_r.q_c, hi/lo bf16 split (err <~ 0.004 abs);
//   margin 0.02+2e-3*T keeps the filter a guaranteed superset; survivors
//   re-scored exactly in f32 -> selection exact (19-bit d2 | 13-bit idx keys,
//   unique, jax tie-break). Scheme numerically validated in R10-R13 (absmax 0).
#define NPTS 8192
#define KNN 8
#define RPB 16            // rows per block
#define THREADS 512
#define STAGES 16
#define SCOLS 512         // cols per stage

typedef __attribute__((ext_vector_type(8))) short bf16x8;
typedef __attribute__((ext_vector_type(4))) float f32x4;

__device__ __forceinline__ unsigned int bf16rne(float v) {
    unsigned int u = __float_as_uint(v);
    return (u + 0x7FFFu + ((u >> 16) & 1u)) >> 16;
}
__device__ __forceinline__ float bf2f(unsigned int h) { return __uint_as_float(h << 16); }

__device__ __forceinline__ void insert8(unsigned int (&best)[KNN], unsigned int key) {
#pragma unroll
    for (int t = 0; t < KNN; ++t) {
        const unsigned int lo = min(best[t], key);
        key = max(best[t], key);
        best[t] = lo;
    }
}

__global__ __launch_bounds__(THREADS) void knn_all(const float* __restrict__ means,
                                                   const float* __restrict__ normals,
                                                   float* __restrict__ out) {
    __shared__ uint4 lds_b[SCOLS * 2];            // 16 KB  [col*2 + kgrp]
    __shared__ unsigned int lds_bits[8][64][5];   // 10 KB  (+pad)
    __shared__ unsigned int thr_k[32][RPB][4];    // 8 KB
    __shared__ unsigned int km[8][RPB][KNN];      // 4 KB
    __shared__ float lds_T[RPB];

    const int tid = threadIdx.x;
    const int l = tid & 63;
    const int wv = __builtin_amdgcn_readfirstlane(tid >> 6);
    const int rb = blockIdx.x * RPB;

    // my row (A-frag + rescore): R = l&15
    const int R = l & 15;
    const int g = l >> 4;
    const int arow = rb + R;
    const float x = means[3 * arow + 0];
    const float y = means[3 * arow + 1];
    const float z = means[3 * arow + 2];
    const float sq = x * x + y * y + z * z;
    const float ax = -2.0f * x, ay = -2.0f * y, az = -2.0f * z;

    // ---- Phase T: per-row threshold from 512 samples (cols = multiples of 16)
    {
        const int trow = tid & 15;
        const int cls = tid >> 4;            // 0..31
        const int trg = rb + trow;
        const float tx = means[3 * trg + 0];
        const float ty = means[3 * trg + 1];
        const float tz = means[3 * trg + 2];
        const float tsq = tx * tx + ty * ty + tz * tz;
        const float bx = -2.0f * tx, by = -2.0f * ty, bz = -2.0f * tz;
        unsigned int b4[4] = {~0u, ~0u, ~0u, ~0u};
#pragma unroll 4
        for (int m = 0; m < 16; ++m) {
            const int col = cls * 256 + m * 16;
            const float qx = means[3 * col + 0];
            const float qy = means[3 * col + 1];
            const float qz = means[3 * col + 2];
            const float qsq = qx * qx + qy * qy + qz * qz;
            const float d2 = fmaxf(fmaf(bx, qx, fmaf(by, qy, fmaf(bz, qz, tsq + qsq))), 0.0f);
            unsigned int key = (__float_as_uint(d2) & 0xFFFFE000u) | (unsigned int)col;
            key = (col == trg) ? ~0u : key;
#pragma unroll
            for (int t = 0; t < 4; ++t) {   // per-thread top-4 (pruning keeps bound valid)
                const unsigned int lo = min(b4[t], key);
                key = max(b4[t], key);
                b4[t] = lo;
            }
        }
#pragma unroll
        for (int j = 0; j < 4; ++j) thr_k[cls][trow][j] = b4[j];
        __syncthreads();
        if (tid < RPB) {
            unsigned int bb[KNN];
#pragma unroll
            for (int s = 0; s < KNN; ++s) bb[s] = ~0u;
            for (int c = 0; c < 32; ++c)
#pragma unroll
                for (int j = 0; j < 4; ++j) insert8(bb, thr_k[c][tid][j]);
            const float Tf = __uint_as_float(bb[7] & 0xFFFFE000u);
            lds_T[tid] = Tf + 0.02f + 2e-3f * Tf;  // covers trunc + mfma error
        }
        __syncthreads();
    }
    float Tmr[4];
#pragma unroll
    for (int r = 0; r < 4; ++r) Tmr[r] = lds_T[g * 4 + r];  // acc rows = g*4+r

    // ---- A fragment (validated R11-13 layout)
    const unsigned int hax = bf16rne(ax), lax = bf16rne(ax - bf2f(hax));
    const unsigned int hay = bf16rne(ay), lay = bf16rne(ay - bf2f(hay));
    const unsigned int haz = bf16rne(az), laz = bf16rne(az - bf2f(haz));
    const unsigned int hsr = bf16rne(sq), lsr = bf16rne(sq - bf2f(hsr));
    uint4 au = make_uint4(0u, 0u, 0u, 0u);
    if (g == 0) au = make_uint4(hax | (hax << 16), lax | (hay << 16),
                                hay | (lay << 16), haz | (haz << 16));
    if (g == 1) au = make_uint4(laz | (0x3F80u << 16), 0x3F80u | (hsr << 16), lsr, 0u);
    union { uint4 u; bf16x8 v; } A; A.u = au;
    const f32x4 zero = {0.0f, 0.0f, 0.0f, 0.0f};

    unsigned int bv[4] = {0u, 0u, 0u, 0u};
    unsigned int best[KNN];
#pragma unroll
    for (int s = 0; s < KNN; ++s) best[s] = ~0u;

    // ---- stage loop: 16 x 512 cols
    for (int s = 0; s < STAGES; ++s) {
        __syncthreads();   // protect lds_b reads of previous stage
        {   // stage + pack: one col per thread
            const int cg = s * SCOLS + tid;
            const float qx = means[3 * cg + 0];
            const float qy = means[3 * cg + 1];
            const float qz = means[3 * cg + 2];
            const float qsq = qx * qx + qy * qy + qz * qz;
            const unsigned int hx = bf16rne(qx), lx = bf16rne(qx - bf2f(hx));
            const unsigned int hy = bf16rne(qy), ly = bf16rne(qy - bf2f(hy));
            const unsigned int hz = bf16rne(qz), lz = bf16rne(qz - bf2f(hz));
            const unsigned int hs = bf16rne(qsq), ls = bf16rne(qsq - bf2f(hs));
            lds_b[tid * 2 + 0] = make_uint4(hx | (lx << 16), hx | (hy << 16),
                                            ly | (hy << 16), hz | (lz << 16));
            lds_b[tid * 2 + 1] = make_uint4(hz | (hs << 16), ls | (0x3F80u << 16), 0x3F80u, 0u);
        }
        __syncthreads();
        const int bbase = wv * 128;   // wave's 64-col band (uint4 units)
#pragma unroll
        for (int m = 0; m < 4; ++m) {
            union { uint4 u; bf16x8 v; } B;
            B.u = lds_b[bbase + m * 32 + R * 2 + (g & 1)];
            const f32x4 acc = __builtin_amdgcn_mfma_f32_16x16x32_bf16(A.v, B.v, zero, 0, 0, 0);
#pragma unroll
            for (int r = 0; r < 4; ++r) bv[r] = bv[r] * 2u + ((acc[r] <= Tmr[r]) ? 1u : 0u);
        }
        if ((s & 7) == 7) {     // decode every 8 stages (32 bits full)
            const int d = s >> 3;
#pragma unroll
            for (int r = 0; r < 4; ++r) { lds_bits[wv][l][r] = bv[r]; bv[r] = 0u; }
            // intra-wave exchange (own wave's writes; no barrier needed)
            const int base_l = (R >> 2) * 16;
#pragma unroll
            for (int cc4 = 0; cc4 < 4; ++cc4) {
                const int cc = g * 4 + cc4;
                unsigned int w = lds_bits[wv][base_l + cc][R & 3];
                while (w) {
                    const int b = __ffs(w) - 1;
                    w &= w - 1;
                    const int t = 31 - b;                 // t = s_local*4 + m
                    const int col = (d * 8 + (t >> 2)) * SCOLS + wv * 64 + (t & 3) * 16 + cc;
                    const float qx = means[3 * col + 0];
                    const float qy = means[3 * col + 1];
                    const float qz = means[3 * col + 2];
                    const float qsq = qx * qx + qy * qy + qz * qz;
                    const float d2 = fmaxf(fmaf(ax, qx, fmaf(ay, qy, fmaf(az, qz, sq + qsq))), 0.0f);
                    unsigned int key = (__float_as_uint(d2) & 0xFFFFE000u) | (unsigned int)col;
                    key = (col == arow) ? ~0u : key;
                    insert8(best, key);
                }
            }
        }
    }

    // ---- merge 4 lanes per row within wave
#pragma unroll
    for (int st = 16; st <= 32; st <<= 1) {
        unsigned int tk[KNN];
#pragma unroll
        for (int s = 0; s < KNN; ++s) tk[s] = __shfl_xor(best[s], st);
#pragma unroll
        for (int s = 0; s < KNN; ++s) insert8(best, tk[s]);
    }
    // ---- merge across 8 waves (LDS tree)
    if (l < RPB) {
#pragma unroll
        for (int s = 0; s < KNN; ++s) km[wv][l][s] = best[s];
    }
    for (int st = 1; st < 8; st <<= 1) {
        __syncthreads();
        if (((wv & (2 * st - 1)) == 0) && l < RPB) {
#pragma unroll
            for (int s = 0; s < KNN; ++s) insert8(best, km[wv + st][l][s]);
#pragma unroll
            for (int s = 0; s < KNN; ++s) km[wv][l][s] = best[s];
        }
    }

    // ---- plane distance + reduce (wave 0, lanes 0..15 hold rows 0..15)
    if (wv == 0 && l < RPB) {
        const float nx = normals[3 * arow + 0];
        const float ny = normals[3 * arow + 1];
        const float nz = normals[3 * arow + 2];
        float sum = 0.0f;
#pragma unroll
        for (int s = 0; s < KNN; ++s) {
            const int nbr = (int)(best[s] & 0x1FFFu);
            const float qx = means[3 * nbr + 0];
            const float qy = means[3 * nbr + 1];
            const float qz = means[3 * nbr + 2];
            sum += fabsf((qx - x) * nx + (qy - y) * ny + (qz - z) * nz);
        }
#pragma unroll
        for (int off = 8; off > 0; off >>= 1) sum += __shfl_down(sum, off);
        if (l == 0) atomicAdd(out, sum * (1.0f / ((float)NPTS * (float)KNN)));
    }
}

extern "C" void kernel_launch(void* const* d_in, const int* in_sizes, int n_in,
                              void* d_out, int out_size, void* d_ws, size_t ws_size,
                              hipStream_t stream) {
    const float* means = (const float*)d_in[0];
    const float* normals = (const float*)d_in[1];
    float* out = (float*)d_out;
    (void)d_ws; (void)ws_size;

    hipMemsetAsync(out, 0, sizeof(float), stream);  // async stream op: graph-capturable
    knn_all<<<NPTS / RPB, THREADS, 0, stream>>>(means, normals, out);
}

// Round 15
// 50.222 us; speedup vs baseline: 1.0151x; 1.0151x over previous
//
#include <hip/hip_runtime.h>
#include <hip/hip_bf16.h>

// N=8192 points, k=8 exact kNN -> mean |plane distance|. Single kernel.
// R15: swapped-operand MFMA filter. A = candidates (from LDS), B = 16 query
// rows (registers). Lane l's 4 acc values = 4 candidates x ONE row (l&15):
// filter bits go straight into the lane's own best[8] via per-stage decode
// from LDS f32 coords (no cross-lane transpose, no global-latency chains).
//   d2(r,c) = sq_r + sq_c - 2 p_r.q_c, hi/lo bf16 split across 13 K-slots
//   (validated R10-R14, absmax 0); margin 0.02+2e-3*T keeps the filter a
//   guaranteed superset; survivors re-scored exactly in f32 -> exact.
#define NPTS 8192
#define KNN 8
#define RPB 16            // rows per block
#define THREADS 1024      // 16 waves; grid 512 -> 2 blocks/CU -> 32 waves/CU
#define STAGES 8
#define SCOLS 1024        // cols per stage; wave band = 64 cols (4 MFMA)

typedef __attribute__((ext_vector_type(8))) short bf16x8;
typedef __attribute__((ext_vector_type(4))) float f32x4;

__device__ __forceinline__ unsigned int bf16rne(float v) {
    unsigned int u = __float_as_uint(v);
    return (u + 0x7FFFu + ((u >> 16) & 1u)) >> 16;
}
__device__ __forceinline__ float bf2f(unsigned int h) { return __uint_as_float(h << 16); }

__device__ __forceinline__ void insert8(unsigned int (&best)[KNN], unsigned int key) {
#pragma unroll
    for (int t = 0; t < KNN; ++t) {
        const unsigned int lo = min(best[t], key);
        key = max(best[t], key);
        best[t] = lo;
    }
}
__device__ __forceinline__ void insert4(unsigned int (&b)[4], unsigned int key) {
#pragma unroll
    for (int t = 0; t < 4; ++t) {
        const unsigned int lo = min(b[t], key);
        key = max(b[t], key);
        b[t] = lo;
    }
}

__global__ __launch_bounds__(THREADS) void knn_all(const float* __restrict__ means,
                                                   const float* __restrict__ normals,
                                                   float* __restrict__ out) {
    // 16KB a0 | 16KB a1 | 16KB ps | 8KB km | 64B T   (thr aliases a0/a1 region)
    __shared__ char smem[57408];
    uint4* a0 = (uint4*)smem;                      // cand kgrp0 frags [1024]
    uint4* a1 = (uint4*)(smem + 16384);            // cand kgrp1 frags [1024]
    float4* ps = (float4*)(smem + 32768);          // cand f32 (x,y,z,sq) [1024]
    unsigned int* km = (unsigned int*)(smem + 49152);   // [16][16][8]
    float* lds_T = (float*)(smem + 57344);         // [16]
    unsigned int* thr = (unsigned int*)smem;       // [64][16][4]  (over a0)
    unsigned int* thr2 = (unsigned int*)(smem + 16384);  // [4][16][8] (over a1)

    const int tid = threadIdx.x;
    const int l = tid & 63;
    const int wv = __builtin_amdgcn_readfirstlane(tid >> 6);
    const int R = l & 15;     // my query row (within block) AND my A-row feed
    const int g = l >> 4;     // k-group / cand-slice
    const int rb = blockIdx.x * RPB;
    const int arow = rb + R;

    // my row f32 data (registers)
    const float x = means[3 * arow + 0];
    const float y = means[3 * arow + 1];
    const float z = means[3 * arow + 2];
    const float sq = x * x + y * y + z * z;
    const float ax = -2.0f * x, ay = -2.0f * y, az = -2.0f * z;

    // ---- threshold: 512 samples/row (cols = multiples of 16), tree merge ----
    {
        const int trow = tid & 15, c64 = tid >> 4;  // 64 sample classes
        const int trg = rb + trow;
        const float tx = means[3 * trg + 0];
        const float ty = means[3 * trg + 1];
        const float tz = means[3 * trg + 2];
        const float tsq = tx * tx + ty * ty + tz * tz;
        const float bx = -2.0f * tx, by = -2.0f * ty, bz = -2.0f * tz;
        unsigned int b4[4] = {~0u, ~0u, ~0u, ~0u};
#pragma unroll
        for (int m = 0; m < 8; ++m) {
            const int col = 16 * (c64 + 64 * m);
            const float qx = means[3 * col + 0];
            const float qy = means[3 * col + 1];
            const float qz = means[3 * col + 2];
            const float qsq = qx * qx + qy * qy + qz * qz;
            const float d2 = fmaxf(fmaf(bx, qx, fmaf(by, qy, fmaf(bz, qz, tsq + qsq))), 0.0f);
            unsigned int key = (__float_as_uint(d2) & 0xFFFFE000u) | (unsigned int)col;
            key = (col == trg) ? ~0u : key;
            insert4(b4, key);   // per-thread top-4 (subset -> bound stays valid)
        }
#pragma unroll
        for (int j = 0; j < 4; ++j) thr[tid * 4 + j] = b4[j];
    }
    __syncthreads();
    if (tid < 256) {            // round 2: 16 keys -> top-8
        const int trow = tid & 15, q = tid >> 4;
        unsigned int bb[KNN];
#pragma unroll
        for (int s = 0; s < KNN; ++s) bb[s] = ~0u;
        for (int c = q * 4; c < q * 4 + 4; ++c)
#pragma unroll
            for (int j = 0; j < 4; ++j) insert8(bb, thr[(c * 16 + trow) * 4 + j]);
#pragma unroll
        for (int s = 0; s < KNN; ++s) km[(q * 16 + trow) * 8 + s] = bb[s];
    }
    __syncthreads();
    if (tid < 64) {             // round 3: 32 keys -> top-8
        const int trow = tid & 15, h = tid >> 4;
        unsigned int bb[KNN];
#pragma unroll
        for (int s = 0; s < KNN; ++s) bb[s] = ~0u;
        for (int q = h * 4; q < h * 4 + 4; ++q)
#pragma unroll
            for (int s = 0; s < KNN; ++s) insert8(bb, km[(q * 16 + trow) * 8 + s]);
#pragma unroll
        for (int s = 0; s < KNN; ++s) thr2[(h * 16 + trow) * 8 + s] = bb[s];
    }
    __syncthreads();
    if (tid < 16) {             // round 4: 32 keys -> top-8 -> T
        unsigned int bb[KNN];
#pragma unroll
        for (int s = 0; s < KNN; ++s) bb[s] = ~0u;
        for (int h = 0; h < 4; ++h)
#pragma unroll
            for (int s = 0; s < KNN; ++s) insert8(bb, thr2[(h * 16 + tid) * 8 + s]);
        const float Tf = __uint_as_float(bb[7] & 0xFFFFE000u);
        lds_T[tid] = Tf + 0.02f + 2e-3f * Tf;   // covers trunc + mfma error
    }
    __syncthreads();
    const float Tm = lds_T[R];

    // ---- B fragment: my row (old-A layout; k-groups 2,3 are zero) ----
    const unsigned int hax = bf16rne(ax), lax = bf16rne(ax - bf2f(hax));
    const unsigned int hay = bf16rne(ay), lay = bf16rne(ay - bf2f(hay));
    const unsigned int haz = bf16rne(az), laz = bf16rne(az - bf2f(haz));
    const unsigned int hsr = bf16rne(sq), lsr = bf16rne(sq - bf2f(hsr));
    uint4 bu = make_uint4(0u, 0u, 0u, 0u);
    if (g == 0) bu = make_uint4(hax | (hax << 16), lax | (hay << 16),
                                hay | (lay << 16), haz | (haz << 16));
    if (g == 1) bu = make_uint4(laz | (0x3F80u << 16), 0x3F80u | (hsr << 16), lsr, 0u);
    union { uint4 u; bf16x8 v; } Bf; Bf.u = bu;
    const f32x4 zero = {0.0f, 0.0f, 0.0f, 0.0f};

    unsigned int best[KNN];
#pragma unroll
    for (int s = 0; s < KNN; ++s) best[s] = ~0u;

    // lanes g==1 feed cand kgrp1; g==0 kgrp0; g>=2 don't-care (B k16-31 == 0)
    const uint4* __restrict__ asel = (g == 1) ? a1 : a0;

    // ---- stage loop: 8 x 1024 cols ----
    for (int s = 0; s < STAGES; ++s) {
        __syncthreads();   // previous stage's ps/a reads complete
        {   // pack one col per thread: frags + f32 coords into LDS
            const int cg = s * SCOLS + tid;
            const float qx = means[3 * cg + 0];
            const float qy = means[3 * cg + 1];
            const float qz = means[3 * cg + 2];
            const float qsq = qx * qx + qy * qy + qz * qz;
            const unsigned int hx = bf16rne(qx), lx = bf16rne(qx - bf2f(hx));
            const unsigned int hy = bf16rne(qy), ly = bf16rne(qy - bf2f(hy));
            const unsigned int hz = bf16rne(qz), lz = bf16rne(qz - bf2f(hz));
            const unsigned int hs = bf16rne(qsq), ls = bf16rne(qsq - bf2f(hs));
            a0[tid] = make_uint4(hx | (lx << 16), hx | (hy << 16),
                                 ly | (hy << 16), hz | (lz << 16));
            a1[tid] = make_uint4(hz | (hs << 16), ls | (0x3F80u << 16), 0x3F80u, 0u);
            ps[tid] = make_float4(qx, qy, qz, qsq);
        }
        __syncthreads();
        unsigned int m16 = 0u;
#pragma unroll
        for (int m = 0; m < 4; ++m) {
            union { uint4 u; bf16x8 v; } Af;
            Af.u = asel[wv * 64 + m * 16 + R];   // A row R of MFMA m
            const f32x4 acc = __builtin_amdgcn_mfma_f32_16x16x32_bf16(Af.v, Bf.v, zero, 0, 0, 0);
#pragma unroll
            for (int r = 0; r < 4; ++r) m16 = m16 * 2u + ((acc[r] <= Tm) ? 1u : 0u);
        }
        // per-stage decode: candidates for MY row, coords still in LDS
        while (m16) {
            const int b = __ffs(m16) - 1;
            m16 &= m16 - 1;
            const int t = 15 - b;                       // t = m*4 + r
            const int cl = wv * 64 + (t >> 2) * 16 + g * 4 + (t & 3);
            const float4 q = ps[cl];
            const float d2 = fmaxf(fmaf(ax, q.x, fmaf(ay, q.y, fmaf(az, q.z, sq + q.w))), 0.0f);
            const int col = s * SCOLS + cl;
            unsigned int key = (__float_as_uint(d2) & 0xFFFFE000u) | (unsigned int)col;
            key = (col == arow) ? ~0u : key;            // drop self
            insert8(best, key);
        }
    }

    // ---- merge the 4 cand-slices of my row within the wave ----
#pragma unroll
    for (int st = 16; st <= 32; st <<= 1) {
        unsigned int tk[KNN];
#pragma unroll
        for (int s = 0; s < KNN; ++s) tk[s] = __shfl_xor(best[s], st);
#pragma unroll
        for (int s = 0; s < KNN; ++s) insert8(best, tk[s]);
    }
    // ---- merge across 16 waves (km reused; tree) ----
    __syncthreads();
    if (l < RPB) {
#pragma unroll
        for (int s = 0; s < KNN; ++s) km[(wv * 16 + l) * 8 + s] = best[s];
    }
    for (int st = 1; st < 16; st <<= 1) {
        __syncthreads();
        if (((wv & (2 * st - 1)) == 0) && l < RPB) {
#pragma unroll
            for (int s = 0; s < KNN; ++s) insert8(best, km[((wv + st) * 16 + l) * 8 + s]);
#pragma unroll
            for (int s = 0; s < KNN; ++s) km[(wv * 16 + l) * 8 + s] = best[s];
        }
    }

    // ---- plane distance + reduce (wave 0) ----
    if (wv == 0) {
        float sum = 0.0f;
        if (l < RPB) {
            const float nx = normals[3 * arow + 0];
            const float ny = normals[3 * arow + 1];
            const float nz = normals[3 * arow + 2];
#pragma unroll
            for (int s = 0; s < KNN; ++s) {
                const int nbr = (int)(best[s] & 0x1FFFu);
                const float qx = means[3 * nbr + 0];
                const float qy = means[3 * nbr + 1];
                const float qz = means[3 * nbr + 2];
                sum += fabsf((qx - x) * nx + (qy - y) * ny + (qz - z) * nz);
            }
        }
#pragma unroll
        for (int off = 8; off > 0; off >>= 1) sum += __shfl_down(sum, off);
        if (l == 0) atomicAdd(out, sum * (1.0f / ((float)NPTS * (float)KNN)));
    }
}

extern "C" void kernel_launch(void* const* d_in, const int* in_sizes, int n_in,
                              void* d_out, int out_size, void* d_ws, size_t ws_size,
                              hipStream_t stream) {
    const float* means = (const float*)d_in[0];
    const float* normals = (const float*)d_in[1];
    float* out = (float*)d_out;
    (void)d_ws; (void)ws_size;

    hipMemsetAsync(out, 0, sizeof(float), stream);
    knn_all<<<NPTS / RPB, THREADS, 0, stream>>>(means, normals, out);
}

// Round 16
// 40.693 us; speedup vs baseline: 1.2528x; 1.2342x over previous
//
#include <hip/hip_runtime.h>
#include <hip/hip_bf16.h>

// N=8192 points, k=8 exact kNN -> mean |plane distance|.
// R16: two kernels. prep_thresh packs pts + candidate frags (cf0/cf1, the
// validated R11-15 layout, de-interleaved) + row frags (rf0/rf1, R15's
// validated swapped-B layout) + per-point thresholds ONCE. mfma_knn streams
// precomputed fragments through LDS (no per-block repacking), 8 MFMAs per
// wave-stage, 32-bit mask -> per-stage decode with exact f32 rescore from pts.
//   d2(r,c) = sq_r + sq_c - 2 p_r.q_c, hi/lo bf16 split over 13 K-slots
//   (absmax 0 in R10-R15); margin 0.02+2e-3*T keeps the filter a guaranteed
//   superset; survivors re-scored exactly in f32 -> selection exact
//   (19-bit d2 | 13-bit idx keys, unique, jax tie-break).
#define NPTS 8192
#define KNN 8
#define RPB 16            // rows per mfma block
#define STAGES 8
#define SCOLS 1024        // cols per stage; wave band = 128 cols = 8 MFMA
#define TSEG 8

typedef __attribute__((ext_vector_type(8))) short bf16x8;
typedef __attribute__((ext_vector_type(4))) float f32x4;

__device__ __forceinline__ unsigned int bf16rne(float v) {
    unsigned int u = __float_as_uint(v);
    return (u + 0x7FFFu + ((u >> 16) & 1u)) >> 16;
}
__device__ __forceinline__ float bf2f(unsigned int h) { return __uint_as_float(h << 16); }

__device__ __forceinline__ void insert8(unsigned int (&best)[KNN], unsigned int key) {
#pragma unroll
    for (int t = 0; t < KNN; ++t) {
        const unsigned int lo = min(best[t], key);
        key = max(best[t], key);
        best[t] = lo;
    }
}

// Pack pts, cand frags (cf0/cf1), row frags (rf0/rf1), thresholds; zero out.
__global__ __launch_bounds__(512) void prep_thresh(const float* __restrict__ means,
                                                   float4* __restrict__ pts,
                                                   uint4* __restrict__ cf0,
                                                   uint4* __restrict__ cf1,
                                                   uint4* __restrict__ rf0,
                                                   uint4* __restrict__ rf1,
                                                   float* __restrict__ Tm_arr,
                                                   float* __restrict__ out) {
    __shared__ unsigned int lds_k[TSEG][64][5];
    const int tid = threadIdx.x;
    const int l = tid & 63;
    const int wv = __builtin_amdgcn_readfirstlane(tid >> 6);
    const int pt = blockIdx.x * 64 + l;
    if (blockIdx.x == 0 && tid == 0) out[0] = 0.0f;

    const float x = means[3 * pt + 0];
    const float y = means[3 * pt + 1];
    const float z = means[3 * pt + 2];
    const float sq = x * x + y * y + z * z;
    if (wv == 0) {
        pts[pt] = make_float4(x, y, z, sq);
        // candidate-side (A-operand) frags
        const unsigned int hx = bf16rne(x), lx = bf16rne(x - bf2f(hx));
        const unsigned int hy = bf16rne(y), ly = bf16rne(y - bf2f(hy));
        const unsigned int hz = bf16rne(z), lz = bf16rne(z - bf2f(hz));
        const unsigned int hs = bf16rne(sq), ls = bf16rne(sq - bf2f(hs));
        cf0[pt] = make_uint4(hx | (lx << 16), hx | (hy << 16),
                             ly | (hy << 16), hz | (lz << 16));
        cf1[pt] = make_uint4(hz | (hs << 16), ls | (0x3F80u << 16), 0x3F80u, 0u);
        // row-side (B-operand) frags: built from -2x,-2y,-2z and sq
        const float ax = -2.0f * x, ay = -2.0f * y, az = -2.0f * z;
        const unsigned int hax = bf16rne(ax), lax = bf16rne(ax - bf2f(hax));
        const unsigned int hay = bf16rne(ay), lay = bf16rne(ay - bf2f(hay));
        const unsigned int haz = bf16rne(az), laz = bf16rne(az - bf2f(haz));
        const unsigned int hsr = bf16rne(sq), lsr = bf16rne(sq - bf2f(hsr));
        rf0[pt] = make_uint4(hax | (hax << 16), lax | (hay << 16),
                             hay | (lay << 16), haz | (haz << 16));
        rf1[pt] = make_uint4(laz | (0x3F80u << 16), 0x3F80u | (hsr << 16), lsr, 0u);
    }

    // threshold: 512 samples/pt, wave-uniform scalar loads (cols 16*(wv+8m))
    const float mx2 = -2.0f * x, my2 = -2.0f * y, mz2 = -2.0f * z;
    unsigned int b4[4] = {~0u, ~0u, ~0u, ~0u};
#pragma unroll 4
    for (int m = 0; m < 64; ++m) {
        const int col = 16 * (wv + TSEG * m);
        const float qx = means[3 * col + 0];
        const float qy = means[3 * col + 1];
        const float qz = means[3 * col + 2];
        const float qsq = qx * qx + qy * qy + qz * qz;
        const float d2 = fmaxf(fmaf(mx2, qx, fmaf(my2, qy, fmaf(mz2, qz, sq + qsq))), 0.0f);
        unsigned int key = (__float_as_uint(d2) & 0xFFFFE000u) | (unsigned int)col;
        key = (col == pt) ? ~0u : key;
#pragma unroll
        for (int t = 0; t < 4; ++t) {  // per-thread top-4 (union still bounds 8th)
            const unsigned int lo = min(b4[t], key);
            key = max(b4[t], key);
            b4[t] = lo;
        }
    }
#pragma unroll
    for (int s = 0; s < 4; ++s) lds_k[wv][l][s] = b4[s];
    __syncthreads();
    if (wv == 0) {
        unsigned int best[KNN] = {b4[0], b4[1], b4[2], b4[3], ~0u, ~0u, ~0u, ~0u};
#pragma unroll
        for (int w = 1; w < TSEG; ++w)
#pragma unroll
            for (int s = 0; s < 4; ++s) insert8(best, lds_k[w][l][s]);
        const float Tf = __uint_as_float(best[7] & 0xFFFFE000u);
        Tm_arr[pt] = Tf + 0.02f + 2e-3f * Tf;  // covers trunc + mfma error
    }
}

// 512 blocks x 512 threads; block owns 16 rows. Stages stream precomputed
// frags through one 32KB LDS buffer (reg-staged, loads overlap compute).
__global__ __launch_bounds__(512) void mfma_knn(const uint4* __restrict__ cf0,
                                                const uint4* __restrict__ cf1,
                                                const uint4* __restrict__ rf0,
                                                const uint4* __restrict__ rf1,
                                                const float4* __restrict__ pts,
                                                const float* __restrict__ Tm_arr,
                                                const float* __restrict__ normals,
                                                float* __restrict__ out) {
    __shared__ uint4 lds_cf[2 * SCOLS];           // 32 KB: [0..1023]=g0, [1024..]=g1
    __shared__ unsigned int km[TSEG][RPB][KNN + 1];
    const int tid = threadIdx.x;
    const int l = tid & 63;
    const int wv = __builtin_amdgcn_readfirstlane(tid >> 6);
    const int R = l & 15;     // my query row (C col = lane&15, validated R15)
    const int g = l >> 4;     // k-group / cand sub-slice
    const int arow = blockIdx.x * RPB + R;

    const float4 mp = pts[arow];
    const float ax = -2.0f * mp.x, ay = -2.0f * mp.y, az = -2.0f * mp.z;
    const float sq = mp.w;
    const float Tm = Tm_arr[arow];

    // B fragment: my row; k16-31 supplied as zero by lanes g>=2
    uint4 bu = make_uint4(0u, 0u, 0u, 0u);
    if (g == 0) bu = rf0[arow];
    else if (g == 1) bu = rf1[arow];
    union { uint4 u; bf16x8 v; } Bf; Bf.u = bu;
    const f32x4 zero = {0.0f, 0.0f, 0.0f, 0.0f};

    unsigned int best[KNN];
#pragma unroll
    for (int s = 0; s < KNN; ++s) best[s] = ~0u;

    // prologue: stage 0 into regs
    uint4 r0a = cf0[tid], r0b = cf0[512 + tid];
    uint4 r1a = cf1[tid], r1b = cf1[512 + tid];

    for (int s = 0; s < STAGES; ++s) {
        __syncthreads();   // A: previous stage's LDS reads complete
        lds_cf[tid] = r0a;            lds_cf[512 + tid] = r0b;
        lds_cf[1024 + tid] = r1a;     lds_cf[1536 + tid] = r1b;
        __syncthreads();   // B: writes visible
        if (s + 1 < STAGES) {         // issue next-stage loads; fly under compute
            const int o = (s + 1) * SCOLS;
            r0a = cf0[o + tid]; r0b = cf0[o + 512 + tid];
            r1a = cf1[o + tid]; r1b = cf1[o + 512 + tid];
        }
        // 8 MFMAs over the wave's 128-col band; lanes g>=2 broadcast-read g0
        const uint4* __restrict__ asel = (g == 1) ? (lds_cf + SCOLS) : lds_cf;
        unsigned int m = 0u;
#pragma unroll
        for (int mt = 0; mt < 8; ++mt) {
            union { uint4 u; bf16x8 v; } Af;
            Af.u = asel[wv * 128 + mt * 16 + R];
            const f32x4 acc = __builtin_amdgcn_mfma_f32_16x16x32_bf16(Af.v, Bf.v, zero, 0, 0, 0);
#pragma unroll
            for (int r = 0; r < 4; ++r) m = m + m + ((acc[r] <= Tm) ? 1u : 0u);
        }
        // decode this stage's 32 bits; exact f32 rescore from pts (L2)
        while (m) {
            const int b = __ffs(m) - 1;
            m &= m - 1;
            const int t = 31 - b;                 // t = mt*4 + r
            const int col = s * SCOLS + wv * 128 + (t >> 2) * 16 + g * 4 + (t & 3);
            const float4 q = pts[col];
            const float d2 = fmaxf(fmaf(ax, q.x, fmaf(ay, q.y, fmaf(az, q.z, sq + q.w))), 0.0f);
            unsigned int key = (__float_as_uint(d2) & 0xFFFFE000u) | (unsigned int)col;
            key = (col == arow) ? ~0u : key;      // drop self
            insert8(best, key);
        }
    }

    // merge the 4 g-lanes sharing this row within the wave
#pragma unroll
    for (int st = 16; st <= 32; st <<= 1) {
        unsigned int tk[KNN];
#pragma unroll
        for (int s = 0; s < KNN; ++s) tk[s] = __shfl_xor(best[s], st);
#pragma unroll
        for (int s = 0; s < KNN; ++s) insert8(best, tk[s]);
    }
    // merge across 8 waves (LDS tree)
    if (l < RPB) {
#pragma unroll
        for (int s = 0; s < KNN; ++s) km[wv][l][s] = best[s];
    }
    for (int st = 1; st < TSEG; st <<= 1) {
        __syncthreads();
        if (((wv & (2 * st - 1)) == 0) && l < RPB) {
#pragma unroll
            for (int s = 0; s < KNN; ++s) insert8(best, km[wv + st][l][s]);
#pragma unroll
            for (int s = 0; s < KNN; ++s) km[wv][l][s] = best[s];
        }
    }

    // finalize: wave 0, lanes 0..15 hold the 16 rows
    if (wv == 0) {
        float sum = 0.0f;
        if (l < RPB) {
            const float nx = normals[3 * arow + 0];
            const float ny = normals[3 * arow + 1];
            const float nz = normals[3 * arow + 2];
#pragma unroll
            for (int s = 0; s < KNN; ++s) {
                const int nbr = (int)(best[s] & 0x1FFFu);
                const float4 q = pts[nbr];
                sum += fabsf((q.x - mp.x) * nx + (q.y - mp.y) * ny + (q.z - mp.z) * nz);
            }
        }
#pragma unroll
        for (int off = 8; off > 0; off >>= 1) sum += __shfl_down(sum, off);
        if (l == 0) atomicAdd(out, sum * (1.0f / ((float)NPTS * (float)KNN)));
    }
}

extern "C" void kernel_launch(void* const* d_in, const int* in_sizes, int n_in,
                              void* d_out, int out_size, void* d_ws, size_t ws_size,
                              hipStream_t stream) {
    const float* means = (const float*)d_in[0];
    const float* normals = (const float*)d_in[1];
    float* out = (float*)d_out;
    char* ws = (char*)d_ws;
    uint4* cf0 = (uint4*)ws;                        // 128 KB
    uint4* cf1 = (uint4*)(ws + 131072);             // 128 KB
    uint4* rf0 = (uint4*)(ws + 262144);             // 128 KB
    uint4* rf1 = (uint4*)(ws + 393216);             // 128 KB
    float4* pts = (float4*)(ws + 524288);           // 128 KB
    float* Tm = (float*)(ws + 655360);              // 32 KB

    prep_thresh<<<NPTS / 64, 512, 0, stream>>>(means, pts, cf0, cf1, rf0, rf1, Tm, out);
    mfma_knn<<<NPTS / RPB, 512, 0, stream>>>(cf0, cf1, rf0, rf1, pts, Tm, normals, out);
}

// Round 17
// 35.018 us; speedup vs baseline: 1.4558x; 1.1621x over previous
//
#include <hip/hip_runtime.h>
#include <hip/hip_bf16.h>

// N=8192 points, k=8 exact kNN -> mean |plane distance|.
// R17: barrier-free MFMA filter. prep packs pts + candidate frags (cf0/cf1)
// + row frags (rf0/rf1) + per-point thresholds once. mfma_knn reads A-frags
// DIRECTLY from L2 (256KB working set; LDS staging was pure overhead) -> no
// __syncthreads in the main loop; waves slide freely for latency cover.
//   d2(r,c) = sq_r + sq_c - 2 p_r.q_c, hi/lo bf16 split over 13 K-slots
//   (absmax 0 across R10-R16); margin 0.02+2e-3*T keeps the filter a
//   guaranteed superset; survivors re-scored exactly in f32 -> selection
//   exact (19-bit d2 | 13-bit idx keys, unique, jax tie-break).
#define NPTS 8192
#define KNN 8
#define RPB 16            // rows per mfma block
#define STAGES 8
#define SCOLS 1024        // cols per stage; wave band = 128 cols = 8 MFMA

typedef __attribute__((ext_vector_type(8))) short bf16x8;
typedef __attribute__((ext_vector_type(4))) float f32x4;

__device__ __forceinline__ unsigned int bf16rne(float v) {
    unsigned int u = __float_as_uint(v);
    return (u + 0x7FFFu + ((u >> 16) & 1u)) >> 16;
}
__device__ __forceinline__ float bf2f(unsigned int h) { return __uint_as_float(h << 16); }

__device__ __forceinline__ void insert8(unsigned int (&best)[KNN], unsigned int key) {
#pragma unroll
    for (int t = 0; t < KNN; ++t) {
        const unsigned int lo = min(best[t], key);
        key = max(best[t], key);
        best[t] = lo;
    }
}
__device__ __forceinline__ void insert4(unsigned int (&b)[4], unsigned int key) {
#pragma unroll
    for (int t = 0; t < 4; ++t) {
        const unsigned int lo = min(b[t], key);
        key = max(b[t], key);
        b[t] = lo;
    }
}

// 256 blocks x 512 threads; 32 points/block; 16 classes x 32 samples each.
// Sample set = {16j : j=0..511} (same validated set as R12-R16).
__global__ __launch_bounds__(512) void prep_thresh(const float* __restrict__ means,
                                                   float4* __restrict__ pts,
                                                   uint4* __restrict__ cf0,
                                                   uint4* __restrict__ cf1,
                                                   uint4* __restrict__ rf0,
                                                   uint4* __restrict__ rf1,
                                                   float* __restrict__ Tm_arr,
                                                   float* __restrict__ out) {
    __shared__ unsigned int lds4[16][32][5];   // per-class top-4 (+pad)
    __shared__ unsigned int lds8[4][32][8];    // round-1 top-8
    const int tid = threadIdx.x;
    const int pl = tid & 31;
    const int cls = tid >> 5;                  // 16 sample classes
    const int pt = blockIdx.x * 32 + pl;
    if (blockIdx.x == 0 && tid == 0) out[0] = 0.0f;

    const float x = means[3 * pt + 0];
    const float y = means[3 * pt + 1];
    const float z = means[3 * pt + 2];
    const float sq = x * x + y * y + z * z;
    if (cls == 0) {
        pts[pt] = make_float4(x, y, z, sq);
        const unsigned int hx = bf16rne(x), lx = bf16rne(x - bf2f(hx));
        const unsigned int hy = bf16rne(y), ly = bf16rne(y - bf2f(hy));
        const unsigned int hz = bf16rne(z), lz = bf16rne(z - bf2f(hz));
        const unsigned int hs = bf16rne(sq), ls = bf16rne(sq - bf2f(hs));
        cf0[pt] = make_uint4(hx | (lx << 16), hx | (hy << 16),
                             ly | (hy << 16), hz | (lz << 16));
        cf1[pt] = make_uint4(hz | (hs << 16), ls | (0x3F80u << 16), 0x3F80u, 0u);
        const float ax = -2.0f * x, ay = -2.0f * y, az = -2.0f * z;
        const unsigned int hax = bf16rne(ax), lax = bf16rne(ax - bf2f(hax));
        const unsigned int hay = bf16rne(ay), lay = bf16rne(ay - bf2f(hay));
        const unsigned int haz = bf16rne(az), laz = bf16rne(az - bf2f(haz));
        const unsigned int hsr = bf16rne(sq), lsr = bf16rne(sq - bf2f(hsr));
        rf0[pt] = make_uint4(hax | (hax << 16), lax | (hay << 16),
                             hay | (lay << 16), haz | (haz << 16));
        rf1[pt] = make_uint4(laz | (0x3F80u << 16), 0x3F80u | (hsr << 16), lsr, 0u);
    }

    // 32 samples/thread at cols 16*(cls + 16*m)
    const float mx2 = -2.0f * x, my2 = -2.0f * y, mz2 = -2.0f * z;
    unsigned int b4[4] = {~0u, ~0u, ~0u, ~0u};
#pragma unroll 4
    for (int m = 0; m < 32; ++m) {
        const int col = 16 * (cls + 16 * m);
        const float qx = means[3 * col + 0];
        const float qy = means[3 * col + 1];
        const float qz = means[3 * col + 2];
        const float qsq = qx * qx + qy * qy + qz * qz;
        const float d2 = fmaxf(fmaf(mx2, qx, fmaf(my2, qy, fmaf(mz2, qz, sq + qsq))), 0.0f);
        unsigned int key = (__float_as_uint(d2) & 0xFFFFE000u) | (unsigned int)col;
        key = (col == pt) ? ~0u : key;
        insert4(b4, key);   // per-thread top-4 (subset pruning keeps T an upper bound)
    }
#pragma unroll
    for (int j = 0; j < 4; ++j) lds4[cls][pl][j] = b4[j];
    __syncthreads();
    if (tid < 128) {        // round 1: 4 classes (16 keys) -> top-8
        const int p2 = tid & 31, q = tid >> 5;
        unsigned int bb[KNN];
#pragma unroll
        for (int s = 0; s < KNN; ++s) bb[s] = ~0u;
        for (int c = q * 4; c < q * 4 + 4; ++c)
#pragma unroll
            for (int j = 0; j < 4; ++j) insert8(bb, lds4[c][p2][j]);
#pragma unroll
        for (int s = 0; s < KNN; ++s) lds8[q][p2][s] = bb[s];
    }
    __syncthreads();
    if (tid < 32) {         // round 2: 32 keys -> top-8 -> T
        unsigned int bb[KNN];
#pragma unroll
        for (int s = 0; s < KNN; ++s) bb[s] = ~0u;
        for (int q = 0; q < 4; ++q)
#pragma unroll
            for (int s = 0; s < KNN; ++s) insert8(bb, lds8[q][tid][s]);
        const float Tf = __uint_as_float(bb[7] & 0xFFFFE000u);
        Tm_arr[blockIdx.x * 32 + tid] = Tf + 0.02f + 2e-3f * Tf;  // trunc + mfma error
    }
}

// 512 blocks x 512 threads; block owns 16 rows; NO barriers in the main loop.
__global__ __launch_bounds__(512) void mfma_knn(const uint4* __restrict__ cf0,
                                                const uint4* __restrict__ cf1,
                                                const uint4* __restrict__ rf0,
                                                const uint4* __restrict__ rf1,
                                                const float4* __restrict__ pts,
                                                const float* __restrict__ Tm_arr,
                                                const float* __restrict__ normals,
                                                float* __restrict__ out) {
    __shared__ unsigned int km[8][RPB][KNN + 1];
    const int tid = threadIdx.x;
    const int l = tid & 63;
    const int wv = __builtin_amdgcn_readfirstlane(tid >> 6);
    const int R = l & 15;     // my query row (C col = lane&15, validated)
    const int g = l >> 4;     // k-group / candidate sub-slice
    const int arow = blockIdx.x * RPB + R;

    const float4 mp = pts[arow];
    const float ax = -2.0f * mp.x, ay = -2.0f * mp.y, az = -2.0f * mp.z;
    const float sq = mp.w;
    const float Tm = Tm_arr[arow];

    // B fragment: my row; lanes g>=2 supply zero (their K-slots unused)
    uint4 bu = make_uint4(0u, 0u, 0u, 0u);
    if (g == 0) bu = rf0[arow];
    else if (g == 1) bu = rf1[arow];
    union { uint4 u; bf16x8 v; } Bf; Bf.u = bu;
    const f32x4 zero = {0.0f, 0.0f, 0.0f, 0.0f};

    // A-fragments straight from L2; g>=2 lanes duplicate g0's address (broadcast)
    const uint4* __restrict__ asel = (g == 1) ? cf1 : cf0;

    unsigned int best[KNN];
#pragma unroll
    for (int s = 0; s < KNN; ++s) best[s] = ~0u;

#pragma unroll 1
    for (int s = 0; s < STAGES; ++s) {
        const int base = s * SCOLS + wv * 128;
        unsigned int m = 0u;
#pragma unroll
        for (int mt = 0; mt < 8; ++mt) {
            union { uint4 u; bf16x8 v; } Af;
            Af.u = asel[base + mt * 16 + R];
            const f32x4 acc = __builtin_amdgcn_mfma_f32_16x16x32_bf16(Af.v, Bf.v, zero, 0, 0, 0);
#pragma unroll
            for (int r = 0; r < 4; ++r) m = m + m + ((acc[r] <= Tm) ? 1u : 0u);
        }
        // decode this stage's 32 bits; exact f32 rescore from pts (L2)
        while (m) {
            const int b = __ffs(m) - 1;
            m &= m - 1;
            const int t = 31 - b;                 // t = mt*4 + r
            const int col = base + (t >> 2) * 16 + g * 4 + (t & 3);
            const float4 q = pts[col];
            const float d2 = fmaxf(fmaf(ax, q.x, fmaf(ay, q.y, fmaf(az, q.z, sq + q.w))), 0.0f);
            unsigned int key = (__float_as_uint(d2) & 0xFFFFE000u) | (unsigned int)col;
            key = (col == arow) ? ~0u : key;      // drop self
            insert8(best, key);
        }
    }

    // merge the 4 g-lanes sharing this row within the wave
#pragma unroll
    for (int st = 16; st <= 32; st <<= 1) {
        unsigned int tk[KNN];
#pragma unroll
        for (int s = 0; s < KNN; ++s) tk[s] = __shfl_xor(best[s], st);
#pragma unroll
        for (int s = 0; s < KNN; ++s) insert8(best, tk[s]);
    }
    // merge across 8 waves (LDS tree)
    if (l < RPB) {
#pragma unroll
        for (int s = 0; s < KNN; ++s) km[wv][l][s] = best[s];
    }
    for (int st = 1; st < 8; st <<= 1) {
        __syncthreads();
        if (((wv & (2 * st - 1)) == 0) && l < RPB) {
#pragma unroll
            for (int s = 0; s < KNN; ++s) insert8(best, km[wv + st][l][s]);
#pragma unroll
            for (int s = 0; s < KNN; ++s) km[wv][l][s] = best[s];
        }
    }

    // finalize: wave 0, lanes 0..15 hold the 16 rows
    if (wv == 0) {
        float sum = 0.0f;
        if (l < RPB) {
            const float nx = normals[3 * arow + 0];
            const float ny = normals[3 * arow + 1];
            const float nz = normals[3 * arow + 2];
#pragma unroll
            for (int s = 0; s < KNN; ++s) {
                const int nbr = (int)(best[s] & 0x1FFFu);
                const float4 q = pts[nbr];
                sum += fabsf((q.x - mp.x) * nx + (q.y - mp.y) * ny + (q.z - mp.z) * nz);
            }
        }
#pragma unroll
        for (int off = 8; off > 0; off >>= 1) sum += __shfl_down(sum, off);
        if (l == 0) atomicAdd(out, sum * (1.0f / ((float)NPTS * (float)KNN)));
    }
}

extern "C" void kernel_launch(void* const* d_in, const int* in_sizes, int n_in,
                              void* d_out, int out_size, void* d_ws, size_t ws_size,
                              hipStream_t stream) {
    const float* means = (const float*)d_in[0];
    const float* normals = (const float*)d_in[1];
    float* out = (float*)d_out;
    char* ws = (char*)d_ws;
    uint4* cf0 = (uint4*)ws;                        // 128 KB
    uint4* cf1 = (uint4*)(ws + 131072);             // 128 KB
    uint4* rf0 = (uint4*)(ws + 262144);             // 128 KB
    uint4* rf1 = (uint4*)(ws + 393216);             // 128 KB
    float4* pts = (float4*)(ws + 524288);           // 128 KB
    float* Tm = (float*)(ws + 655360);              // 32 KB

    prep_thresh<<<NPTS / 32, 512, 0, stream>>>(means, pts, cf0, cf1, rf0, rf1, Tm, out);
    mfma_knn<<<NPTS / RPB, 512, 0, stream>>>(cf0, cf1, rf0, rf1, pts, Tm, normals, out);
}

// Round 18
// 34.953 us; speedup vs baseline: 1.4585x; 1.0019x over previous
//
#include <hip/hip_runtime.h>
#include <hip/hip_bf16.h>

// N=8192 points, k=8 exact kNN -> mean |plane distance|.
// R18: R17 + software-pipelined A-frag stream (register double-buffer, no
// LDS), setprio around the MFMA cluster, memset node removed.
//   d2(r,c) = sq_r + sq_c - 2 p_r.q_c, hi/lo bf16 split over 13 K-slots
//   (absmax 0 across R10-R17); margin 0.02+2e-3*T keeps the filter a
//   guaranteed superset; survivors re-scored exactly in f32 -> selection
//   exact (19-bit d2 | 13-bit idx keys, unique, jax tie-break).
#define NPTS 8192
#define KNN 8
#define RPB 16            // rows per mfma block
#define STAGES 8
#define SCOLS 1024        // cols per stage; wave band = 128 cols = 8 MFMA

typedef __attribute__((ext_vector_type(8))) short bf16x8;
typedef __attribute__((ext_vector_type(4))) float f32x4;

__device__ __forceinline__ unsigned int bf16rne(float v) {
    unsigned int u = __float_as_uint(v);
    return (u + 0x7FFFu + ((u >> 16) & 1u)) >> 16;
}
__device__ __forceinline__ float bf2f(unsigned int h) { return __uint_as_float(h << 16); }

__device__ __forceinline__ void insert8(unsigned int (&best)[KNN], unsigned int key) {
#pragma unroll
    for (int t = 0; t < KNN; ++t) {
        const unsigned int lo = min(best[t], key);
        key = max(best[t], key);
        best[t] = lo;
    }
}
__device__ __forceinline__ void insert4(unsigned int (&b)[4], unsigned int key) {
#pragma unroll
    for (int t = 0; t < 4; ++t) {
        const unsigned int lo = min(b[t], key);
        key = max(b[t], key);
        b[t] = lo;
    }
}

// 256 blocks x 512 threads; 32 points/block; 16 classes x 32 samples each.
// Sample set = {16j : j=0..511} (same validated set as R12-R17).
__global__ __launch_bounds__(512) void prep_thresh(const float* __restrict__ means,
                                                   float4* __restrict__ pts,
                                                   uint4* __restrict__ cf0,
                                                   uint4* __restrict__ cf1,
                                                   uint4* __restrict__ rf0,
                                                   uint4* __restrict__ rf1,
                                                   float* __restrict__ Tm_arr,
                                                   float* __restrict__ out) {
    __shared__ unsigned int lds4[16][32][5];   // per-class top-4 (+pad)
    __shared__ unsigned int lds8[4][32][8];    // round-1 top-8
    const int tid = threadIdx.x;
    const int pl = tid & 31;
    const int cls = tid >> 5;                  // 16 sample classes
    const int pt = blockIdx.x * 32 + pl;
    if (blockIdx.x == 0 && tid == 0) out[0] = 0.0f;

    const float x = means[3 * pt + 0];
    const float y = means[3 * pt + 1];
    const float z = means[3 * pt + 2];
    const float sq = x * x + y * y + z * z;
    if (cls == 0) {
        pts[pt] = make_float4(x, y, z, sq);
        const unsigned int hx = bf16rne(x), lx = bf16rne(x - bf2f(hx));
        const unsigned int hy = bf16rne(y), ly = bf16rne(y - bf2f(hy));
        const unsigned int hz = bf16rne(z), lz = bf16rne(z - bf2f(hz));
        const unsigned int hs = bf16rne(sq), ls = bf16rne(sq - bf2f(hs));
        cf0[pt] = make_uint4(hx | (lx << 16), hx | (hy << 16),
                             ly | (hy << 16), hz | (lz << 16));
        cf1[pt] = make_uint4(hz | (hs << 16), ls | (0x3F80u << 16), 0x3F80u, 0u);
        const float ax = -2.0f * x, ay = -2.0f * y, az = -2.0f * z;
        const unsigned int hax = bf16rne(ax), lax = bf16rne(ax - bf2f(hax));
        const unsigned int hay = bf16rne(ay), lay = bf16rne(ay - bf2f(hay));
        const unsigned int haz = bf16rne(az), laz = bf16rne(az - bf2f(haz));
        const unsigned int hsr = bf16rne(sq), lsr = bf16rne(sq - bf2f(hsr));
        rf0[pt] = make_uint4(hax | (hax << 16), lax | (hay << 16),
                             hay | (lay << 16), haz | (haz << 16));
        rf1[pt] = make_uint4(laz | (0x3F80u << 16), 0x3F80u | (hsr << 16), lsr, 0u);
    }

    // 32 samples/thread at cols 16*(cls + 16*m)
    const float mx2 = -2.0f * x, my2 = -2.0f * y, mz2 = -2.0f * z;
    unsigned int b4[4] = {~0u, ~0u, ~0u, ~0u};
#pragma unroll 4
    for (int m = 0; m < 32; ++m) {
        const int col = 16 * (cls + 16 * m);
        const float qx = means[3 * col + 0];
        const float qy = means[3 * col + 1];
        const float qz = means[3 * col + 2];
        const float qsq = qx * qx + qy * qy + qz * qz;
        const float d2 = fmaxf(fmaf(mx2, qx, fmaf(my2, qy, fmaf(mz2, qz, sq + qsq))), 0.0f);
        unsigned int key = (__float_as_uint(d2) & 0xFFFFE000u) | (unsigned int)col;
        key = (col == pt) ? ~0u : key;
        insert4(b4, key);   // per-thread top-4 (subset pruning keeps T an upper bound)
    }
#pragma unroll
    for (int j = 0; j < 4; ++j) lds4[cls][pl][j] = b4[j];
    __syncthreads();
    if (tid < 128) {        // round 1: 4 classes (16 keys) -> top-8
        const int p2 = tid & 31, q = tid >> 5;
        unsigned int bb[KNN];
#pragma unroll
        for (int s = 0; s < KNN; ++s) bb[s] = ~0u;
        for (int c = q * 4; c < q * 4 + 4; ++c)
#pragma unroll
            for (int j = 0; j < 4; ++j) insert8(bb, lds4[c][p2][j]);
#pragma unroll
        for (int s = 0; s < KNN; ++s) lds8[q][p2][s] = bb[s];
    }
    __syncthreads();
    if (tid < 32) {         // round 2: 32 keys -> top-8 -> T
        unsigned int bb[KNN];
#pragma unroll
        for (int s = 0; s < KNN; ++s) bb[s] = ~0u;
        for (int q = 0; q < 4; ++q)
#pragma unroll
            for (int s = 0; s < KNN; ++s) insert8(bb, lds8[q][tid][s]);
        const float Tf = __uint_as_float(bb[7] & 0xFFFFE000u);
        Tm_arr[blockIdx.x * 32 + tid] = Tf + 0.02f + 2e-3f * Tf;  // trunc + mfma error
    }
}

// 512 blocks x 512 threads; block owns 16 rows; barrier-free main loop with
// register-double-buffered A-frag stream.
__global__ __launch_bounds__(512, 4) void mfma_knn(const uint4* __restrict__ cf0,
                                                   const uint4* __restrict__ cf1,
                                                   const uint4* __restrict__ rf0,
                                                   const uint4* __restrict__ rf1,
                                                   const float4* __restrict__ pts,
                                                   const float* __restrict__ Tm_arr,
                                                   const float* __restrict__ normals,
                                                   float* __restrict__ out) {
    __shared__ unsigned int km[8][RPB][KNN + 1];
    const int tid = threadIdx.x;
    const int l = tid & 63;
    const int wv = __builtin_amdgcn_readfirstlane(tid >> 6);
    const int R = l & 15;     // my query row
    const int g = l >> 4;     // k-group / candidate sub-slice
    const int arow = blockIdx.x * RPB + R;

    const float4 mp = pts[arow];
    const float ax = -2.0f * mp.x, ay = -2.0f * mp.y, az = -2.0f * mp.z;
    const float sq = mp.w;
    const float Tm = Tm_arr[arow];

    // B fragment: my row; lanes g>=2 supply zero (their K-slots unused)
    uint4 bu = make_uint4(0u, 0u, 0u, 0u);
    if (g == 0) bu = rf0[arow];
    else if (g == 1) bu = rf1[arow];
    union { uint4 u; bf16x8 v; } Bf; Bf.u = bu;
    const f32x4 zero = {0.0f, 0.0f, 0.0f, 0.0f};

    // A-fragments straight from L2; g>=2 lanes duplicate g0's address (broadcast)
    const uint4* __restrict__ asel = (g == 1) ? cf1 : cf0;
    const int lofs = wv * 128 + R;

    unsigned int best[KNN];
#pragma unroll
    for (int s = 0; s < KNN; ++s) best[s] = ~0u;

    // prologue: stage 0 fragments
    uint4 c0 = asel[lofs + 0],   c1 = asel[lofs + 16],  c2 = asel[lofs + 32],
          c3 = asel[lofs + 48],  c4 = asel[lofs + 64],  c5 = asel[lofs + 80],
          c6 = asel[lofs + 96],  c7 = asel[lofs + 112];

#define KSTEP(CC)                                                                     \
    {                                                                                 \
        union { uint4 u; bf16x8 v; } Af; Af.u = (CC);                                 \
        const f32x4 acc = __builtin_amdgcn_mfma_f32_16x16x32_bf16(Af.v, Bf.v, zero, 0, 0, 0); \
        m = m + m + ((acc[0] <= Tm) ? 1u : 0u);                                       \
        m = m + m + ((acc[1] <= Tm) ? 1u : 0u);                                       \
        m = m + m + ((acc[2] <= Tm) ? 1u : 0u);                                       \
        m = m + m + ((acc[3] <= Tm) ? 1u : 0u);                                       \
    }

#pragma unroll 1
    for (int s = 0; s < STAGES; ++s) {
        // issue next-stage prefetch (wraps to stage 0 on last iter; discarded)
        const int nofs = ((s + 1) & (STAGES - 1)) * SCOLS + lofs;
        const uint4 n0 = asel[nofs + 0],   n1 = asel[nofs + 16];
        const uint4 n2 = asel[nofs + 32],  n3 = asel[nofs + 48];
        const uint4 n4 = asel[nofs + 64],  n5 = asel[nofs + 80];
        const uint4 n6 = asel[nofs + 96],  n7 = asel[nofs + 112];

        unsigned int m = 0u;
        __builtin_amdgcn_s_setprio(1);
        KSTEP(c0) KSTEP(c1) KSTEP(c2) KSTEP(c3)
        KSTEP(c4) KSTEP(c5) KSTEP(c6) KSTEP(c7)
        __builtin_amdgcn_s_setprio(0);

        // decode this stage's 32 bits; exact f32 rescore from pts (L2)
        const int base = s * SCOLS + wv * 128;
        while (m) {
            const int b = __ffs(m) - 1;
            m &= m - 1;
            const int t = 31 - b;                 // t = mt*4 + r
            const int col = base + (t >> 2) * 16 + g * 4 + (t & 3);
            const float4 q = pts[col];
            const float d2 = fmaxf(fmaf(ax, q.x, fmaf(ay, q.y, fmaf(az, q.z, sq + q.w))), 0.0f);
            unsigned int key = (__float_as_uint(d2) & 0xFFFFE000u) | (unsigned int)col;
            key = (col == arow) ? ~0u : key;      // drop self
            insert8(best, key);
        }

        c0 = n0; c1 = n1; c2 = n2; c3 = n3;
        c4 = n4; c5 = n5; c6 = n6; c7 = n7;
    }
#undef KSTEP

    // merge the 4 g-lanes sharing this row within the wave
#pragma unroll
    for (int st = 16; st <= 32; st <<= 1) {
        unsigned int tk[KNN];
#pragma unroll
        for (int s = 0; s < KNN; ++s) tk[s] = __shfl_xor(best[s], st);
#pragma unroll
        for (int s = 0; s < KNN; ++s) insert8(best, tk[s]);
    }
    // merge across 8 waves (LDS tree)
    if (l < RPB) {
#pragma unroll
        for (int s = 0; s < KNN; ++s) km[wv][l][s] = best[s];
    }
    for (int st = 1; st < 8; st <<= 1) {
        __syncthreads();
        if (((wv & (2 * st - 1)) == 0) && l < RPB) {
#pragma unroll
            for (int s = 0; s < KNN; ++s) insert8(best, km[wv + st][l][s]);
#pragma unroll
            for (int s = 0; s < KNN; ++s) km[wv][l][s] = best[s];
        }
    }

    // finalize: wave 0, lanes 0..15 hold the 16 rows
    if (wv == 0) {
        float sum = 0.0f;
        if (l < RPB) {
            const float nx = normals[3 * arow + 0];
            const float ny = normals[3 * arow + 1];
            const float nz = normals[3 * arow + 2];
#pragma unroll
            for (int s = 0; s < KNN; ++s) {
                const int nbr = (int)(best[s] & 0x1FFFu);
                const float4 q = pts[nbr];
                sum += fabsf((q.x - mp.x) * nx + (q.y - mp.y) * ny + (q.z - mp.z) * nz);
            }
        }
#pragma unroll
        for (int off = 8; off > 0; off >>= 1) sum += __shfl_down(sum, off);
        if (l == 0) atomicAdd(out, sum * (1.0f / ((float)NPTS * (float)KNN)));
    }
}

extern "C" void kernel_launch(void* const* d_in, const int* in_sizes, int n_in,
                              void* d_out, int out_size, void* d_ws, size_t ws_size,
                              hipStream_t stream) {
    const float* means = (const float*)d_in[0];
    const float* normals = (const float*)d_in[1];
    float* out = (float*)d_out;
    char* ws = (char*)d_ws;
    uint4* cf0 = (uint4*)ws;                        // 128 KB
    uint4* cf1 = (uint4*)(ws + 131072);             // 128 KB
    uint4* rf0 = (uint4*)(ws + 262144);             // 128 KB
    uint4* rf1 = (uint4*)(ws + 393216);             // 128 KB
    float4* pts = (float4*)(ws + 524288);           // 128 KB
    float* Tm = (float*)(ws + 655360);              // 32 KB

    prep_thresh<<<NPTS / 32, 512, 0, stream>>>(means, pts, cf0, cf1, rf0, rf1, Tm, out);
    mfma_knn<<<NPTS / RPB, 512, 0, stream>>>(cf0, cf1, rf0, rf1, pts, Tm, normals, out);
}